// Round 1
// baseline (76.421 us; speedup 1.0000x reference)
//
#include <hip/hip_runtime.h>

// Eval-mode stochastic pooling, 2x2 non-overlapping windows:
// out[b,c,i,j] = sum(x^2) / sum(x) over the window.
// Input  (16,96,224,224) f32, Output (16,96,112,112) f32. Memory-bound.

__global__ __launch_bounds__(256) void spool2x2_kernel(
    const float* __restrict__ in, float* __restrict__ out, unsigned n4) {
    unsigned idx    = blockIdx.x * blockDim.x + threadIdx.x;
    unsigned stride = gridDim.x * blockDim.x;
    for (; idx < n4; idx += stride) {
        // idx indexes float4 groups of the output: 112/4 = 28 per output row.
        unsigned q = idx / 28u;          // global output-row id (bc*112 + i)
        unsigned r = idx - q * 28u;      // vec4 column within the row
        // input top-row float offset = bc*224*224 + (2i)*224 + 8r = 448*q + 8*r
        // (since 224*224 = 448*112, the bc/i split cancels)
        unsigned base = q * 448u + r * 8u;
        const float4* top = reinterpret_cast<const float4*>(in + base);
        const float4* bot = reinterpret_cast<const float4*>(in + base + 224u);
        float4 t0 = top[0];
        float4 t1 = top[1];
        float4 b0 = bot[0];
        float4 b1 = bot[1];
        float4 o;
        {
            float s  = t0.x + t0.y + b0.x + b0.y;
            float sq = t0.x * t0.x + t0.y * t0.y + b0.x * b0.x + b0.y * b0.y;
            o.x = sq / s;
        }
        {
            float s  = t0.z + t0.w + b0.z + b0.w;
            float sq = t0.z * t0.z + t0.w * t0.w + b0.z * b0.z + b0.w * b0.w;
            o.y = sq / s;
        }
        {
            float s  = t1.x + t1.y + b1.x + b1.y;
            float sq = t1.x * t1.x + t1.y * t1.y + b1.x * b1.x + b1.y * b1.y;
            o.z = sq / s;
        }
        {
            float s  = t1.z + t1.w + b1.z + b1.w;
            float sq = t1.z * t1.z + t1.w * t1.w + b1.z * b1.z + b1.w * b1.w;
            o.w = sq / s;
        }
        reinterpret_cast<float4*>(out)[idx] = o;
    }
}

extern "C" void kernel_launch(void* const* d_in, const int* in_sizes, int n_in,
                              void* d_out, int out_size, void* d_ws, size_t ws_size,
                              hipStream_t stream) {
    const float* x = (const float*)d_in[0];
    float* out = (float*)d_out;
    unsigned n4 = (unsigned)(out_size / 4);  // 19,267,584 / 4 = 4,816,896
    int block = 256;
    unsigned grid = (n4 + block - 1) / block;
    if (grid > 2048u) grid = 2048u;          // 8 blocks/CU, grid-stride the rest
    spool2x2_kernel<<<dim3(grid), dim3(block), 0, stream>>>(x, out, n4);
}

// Round 3
// 71.780 us; speedup vs baseline: 1.0647x; 1.0647x over previous
//
#include <hip/hip_runtime.h>

// Eval-mode stochastic pooling, 2x2 non-overlapping windows:
// out[b,c,i,j] = sum(x^2) / sum(x) over the window.
// Input (16,96,224,224) f32, Output (16,96,112,112) f32. Purely HBM-bound.
//
// Mapping: one thread-iteration = one float4 of the TOP row + the matching
// float4 of the BOTTOM row (16B dense per load instruction across the wave)
// -> one float2 of output (8B dense store). All traffic streamed once ->
// nontemporal hints. Native clang vector types (HIP_vector_type is a struct
// and is rejected by __builtin_nontemporal_*).

typedef float f32x4 __attribute__((ext_vector_type(4)));
typedef float f32x2 __attribute__((ext_vector_type(2)));

__global__ __launch_bounds__(256) void spool2x2_kernel(
    const float* __restrict__ in, float* __restrict__ out, unsigned n2) {
    unsigned idx    = blockIdx.x * blockDim.x + threadIdx.x;
    unsigned stride = gridDim.x * blockDim.x;
    for (; idx < n2; idx += stride) {
        // idx indexes float2 groups of the output: 112/2 = 56 per output row.
        unsigned q = idx / 56u;          // global output-row id (bc*112 + i)
        unsigned r = idx - q * 56u;      // float2 column within the row
        // input top-row float offset = bc*224*224 + (2i)*224 + 4r = 448*q + 4*r
        // (224*224 = 448*112, so the bc/i split cancels)
        unsigned base = q * 448u + r * 4u;
        f32x4 t = __builtin_nontemporal_load(
            reinterpret_cast<const f32x4*>(in + base));
        f32x4 b = __builtin_nontemporal_load(
            reinterpret_cast<const f32x4*>(in + base + 224u));
        f32x2 o;
        o.x = (t.x * t.x + t.y * t.y + b.x * b.x + b.y * b.y) /
              (t.x + t.y + b.x + b.y);
        o.y = (t.z * t.z + t.w * t.w + b.z * b.z + b.w * b.w) /
              (t.z + t.w + b.z + b.w);
        __builtin_nontemporal_store(o, reinterpret_cast<f32x2*>(out) + idx);
    }
}

extern "C" void kernel_launch(void* const* d_in, const int* in_sizes, int n_in,
                              void* d_out, int out_size, void* d_ws, size_t ws_size,
                              hipStream_t stream) {
    const float* x = (const float*)d_in[0];
    float* out = (float*)d_out;
    unsigned n2 = (unsigned)(out_size / 2);  // 19,267,584 / 2 = 9,633,792
    int block = 256;
    unsigned grid = (n2 + block - 1) / block;
    if (grid > 2048u) grid = 2048u;          // 8 blocks/CU, grid-stride the rest
    spool2x2_kernel<<<dim3(grid), dim3(block), 0, stream>>>(x, out, n2);
}

// Round 4
// 71.217 us; speedup vs baseline: 1.0731x; 1.0079x over previous
//
#include <hip/hip_runtime.h>

// Eval-mode stochastic pooling, 2x2 non-overlapping windows:
// out[b,c,i,j] = sum(x^2) / sum(x) over the window.
// Input (16,96,224,224) f32, Output (16,96,112,112) f32. Purely HBM-bound.
//
// Mapping: one unit = one float4 of the TOP row + matching float4 of the
// BOTTOM row (16B dense per load instruction across the wave) -> one float2
// of output (8B dense store). Streamed once -> nontemporal.
//
// T = gridDim*blockDim is a multiple of 56 (= float2s per output row), so the
// within-row position r is grid-stride-invariant and the input base advances
// by a constant per stride: no integer division in the loop. Division replaced
// by v_rcp_f32 (rel err ~2.4e-7, threshold 2e-2). Unroll x4 for 8 loads in
// flight per wave.

typedef float f32x4 __attribute__((ext_vector_type(4)));
typedef float f32x2 __attribute__((ext_vector_type(2)));

#define BLOCKS 2044u   // 2044*256 = 523264 = 56 * 9344 (multiple of 56!)

__device__ __forceinline__ f32x2 pool_unit(const float* __restrict__ in,
                                           unsigned base) {
    f32x4 t = __builtin_nontemporal_load(
        reinterpret_cast<const f32x4*>(in + base));
    f32x4 b = __builtin_nontemporal_load(
        reinterpret_cast<const f32x4*>(in + base + 224u));
    f32x2 o;
    float s0 = (t.x + t.y) + (b.x + b.y);
    float q0 = (t.x * t.x + t.y * t.y) + (b.x * b.x + b.y * b.y);
    float s1 = (t.z + t.w) + (b.z + b.w);
    float q1 = (t.z * t.z + t.w * t.w) + (b.z * b.z + b.w * b.w);
    o.x = q0 * __builtin_amdgcn_rcpf(s0);
    o.y = q1 * __builtin_amdgcn_rcpf(s1);
    return o;
}

__global__ __launch_bounds__(256) void spool2x2_kernel(
    const float* __restrict__ in, float* __restrict__ out, unsigned n2) {
    const unsigned T = gridDim.x * blockDim.x;       // multiple of 56
    const unsigned BSTEP = (T / 56u) * 448u;         // base advance per stride
    unsigned idx = blockIdx.x * blockDim.x + threadIdx.x;
    unsigned q = idx / 56u;                          // once, outside the loop
    unsigned r = idx - q * 56u;
    unsigned base = q * 448u + r * 4u;               // top-row float offset
    f32x2* __restrict__ o2 = reinterpret_cast<f32x2*>(out);

    // main: 4 independent units per iteration (8 loads in flight)
    for (; idx + 3u * T < n2; idx += 4u * T, base += 4u * BSTEP) {
        f32x2 o0 = pool_unit(in, base);
        f32x2 o1 = pool_unit(in, base + BSTEP);
        f32x2 oo2 = pool_unit(in, base + 2u * BSTEP);
        f32x2 o3 = pool_unit(in, base + 3u * BSTEP);
        __builtin_nontemporal_store(o0, o2 + idx);
        __builtin_nontemporal_store(o1, o2 + idx + T);
        __builtin_nontemporal_store(oo2, o2 + idx + 2u * T);
        __builtin_nontemporal_store(o3, o2 + idx + 3u * T);
    }
    // tail
    for (; idx < n2; idx += T, base += BSTEP) {
        __builtin_nontemporal_store(pool_unit(in, base), o2 + idx);
    }
}

extern "C" void kernel_launch(void* const* d_in, const int* in_sizes, int n_in,
                              void* d_out, int out_size, void* d_ws, size_t ws_size,
                              hipStream_t stream) {
    const float* x = (const float*)d_in[0];
    float* out = (float*)d_out;
    unsigned n2 = (unsigned)(out_size / 2);  // 9,633,792 float2 units
    spool2x2_kernel<<<dim3(BLOCKS), dim3(256), 0, stream>>>(x, out, n2);
}

// Round 5
// 63.977 us; speedup vs baseline: 1.1945x; 1.1132x over previous
//
#include <hip/hip_runtime.h>

// Eval-mode stochastic pooling, 2x2 non-overlapping windows:
// out[b,c,i,j] = sum(x^2) / sum(x) over the window.
// Input (16,96,224,224) f32, Output (16,96,112,112) f32. Purely HBM-bound.
//
// A/B vs R3: loads are now CACHED (no nontemporal) so the 308 MB input can
// be partially retained in the 256 MB Infinity Cache across graph replays;
// stores stay nontemporal (output is write-once-per-replay, keep it from
// evicting the input). Everything else identical to R3/R4.

typedef float f32x4 __attribute__((ext_vector_type(4)));
typedef float f32x2 __attribute__((ext_vector_type(2)));

#define BLOCKS 2044u   // 2044*256 = 523264 = 56 * 9344 (multiple of 56!)

__device__ __forceinline__ f32x2 pool_unit(const float* __restrict__ in,
                                           unsigned base) {
    f32x4 t = *reinterpret_cast<const f32x4*>(in + base);          // cached
    f32x4 b = *reinterpret_cast<const f32x4*>(in + base + 224u);   // cached
    f32x2 o;
    float s0 = (t.x + t.y) + (b.x + b.y);
    float q0 = (t.x * t.x + t.y * t.y) + (b.x * b.x + b.y * b.y);
    float s1 = (t.z + t.w) + (b.z + b.w);
    float q1 = (t.z * t.z + t.w * t.w) + (b.z * b.z + b.w * b.w);
    o.x = q0 * __builtin_amdgcn_rcpf(s0);
    o.y = q1 * __builtin_amdgcn_rcpf(s1);
    return o;
}

__global__ __launch_bounds__(256) void spool2x2_kernel(
    const float* __restrict__ in, float* __restrict__ out, unsigned n2) {
    const unsigned T = gridDim.x * blockDim.x;       // multiple of 56
    const unsigned BSTEP = (T / 56u) * 448u;         // base advance per stride
    unsigned idx = blockIdx.x * blockDim.x + threadIdx.x;
    unsigned q = idx / 56u;                          // once, outside the loop
    unsigned r = idx - q * 56u;
    unsigned base = q * 448u + r * 4u;               // top-row float offset
    f32x2* __restrict__ o2 = reinterpret_cast<f32x2*>(out);

    // main: 4 independent units per iteration (8 loads in flight)
    for (; idx + 3u * T < n2; idx += 4u * T, base += 4u * BSTEP) {
        f32x2 o0 = pool_unit(in, base);
        f32x2 o1 = pool_unit(in, base + BSTEP);
        f32x2 oo2 = pool_unit(in, base + 2u * BSTEP);
        f32x2 o3 = pool_unit(in, base + 3u * BSTEP);
        __builtin_nontemporal_store(o0, o2 + idx);
        __builtin_nontemporal_store(o1, o2 + idx + T);
        __builtin_nontemporal_store(oo2, o2 + idx + 2u * T);
        __builtin_nontemporal_store(o3, o2 + idx + 3u * T);
    }
    // tail
    for (; idx < n2; idx += T, base += BSTEP) {
        __builtin_nontemporal_store(pool_unit(in, base), o2 + idx);
    }
}

extern "C" void kernel_launch(void* const* d_in, const int* in_sizes, int n_in,
                              void* d_out, int out_size, void* d_ws, size_t ws_size,
                              hipStream_t stream) {
    const float* x = (const float*)d_in[0];
    float* out = (float*)d_out;
    unsigned n2 = (unsigned)(out_size / 2);  // 9,633,792 float2 units
    spool2x2_kernel<<<dim3(BLOCKS), dim3(256), 0, stream>>>(x, out, n2);
}